// Round 1
// baseline (56.848 us; speedup 1.0000x reference)
//
#include <hip/hip_runtime.h>

// DIM_backprop: depth (B,H,W) fp32 -> BEV soft histogram (B,W,D) fp32.
// sigma=0.5, bin spacing=20 => Gaussian underflows fp32 beyond the single
// nearest bin (second-nearest is >=13.3 away: exp(-2*13.3^2)=0 in fp32).
// So we scatter exactly one value per valid pixel instead of the reference's
// dense (B,H,W,D) = 123M exp evaluations.

#define BB 16
#define HH 120
#define WW 160
#define DD 401

#define DEPTH_MAX 8000.0f
#define INV_BIN 0.05f          // 1/20
#define SIG_EPS 0.50000001f    // sigma + 1e-8
#define ZERO_EPS 1e-6f

__global__ __launch_bounds__(256)
void dim_bev_kernel(const float* __restrict__ depth, float* __restrict__ out) {
    __shared__ float hist[DD];
    const int col = blockIdx.x;          // b*WW + w
    const int b = col / WW;
    const int w = col - b * WW;
    const int tid = threadIdx.x;

    // zero LDS histogram
    for (int i = tid; i < DD; i += 256) hist[i] = 0.0f;
    __syncthreads();

    if (tid < HH) {
        const float d = depth[(b * HH + tid) * WW + w];
        const bool valid = isfinite(d) && (d <= DEPTH_MAX) && (d > ZERO_EPS);
        if (valid) {
            int bin = __float2int_rn(d * INV_BIN);
            bin = bin < 0 ? 0 : (bin > DD - 1 ? DD - 1 : bin);
            const float x = (float)bin * 20.0f - d;
            const float z = x * (1.0f / SIG_EPS);
            // 1/((sigma+eps)*sqrt(2*pi))
            const float norm = 1.0f / (SIG_EPS * 2.50662827463100050242f);
            const float g = __expf(-0.5f * z * z) * norm;
            if (g > 0.0f) atomicAdd(&hist[bin], g);
        }
    }
    __syncthreads();

    // coalesced write of this (b,w) column's D bins
    float* o = out + (size_t)col * DD;
    for (int i = tid; i < DD; i += 256) o[i] = hist[i];
}

extern "C" void kernel_launch(void* const* d_in, const int* in_sizes, int n_in,
                              void* d_out, int out_size, void* d_ws, size_t ws_size,
                              hipStream_t stream) {
    const float* depth = (const float*)d_in[0];
    float* out = (float*)d_out;
    dim_bev_kernel<<<BB * WW, 256, 0, stream>>>(depth, out);
}

// Round 2
// 55.847 us; speedup vs baseline: 1.0179x; 1.0179x over previous
//
#include <hip/hip_runtime.h>

// DIM_backprop: depth (B,H,W) fp32 -> BEV soft histogram (B,W,D) fp32.
// sigma=0.5, bin spacing=20 => Gaussian underflows fp32 beyond the single
// nearest bin (second-nearest bin is >=13.3 sigma-units*... exp(-2*13.3^2)=0
// in fp32). So exactly one bin per valid pixel is nonzero: scatter, don't
// densely evaluate (B,H,W,D).
//
// R1: W_TILE=4 columns/block. LDS hist[4][401] flat == the block's contiguous
// 1604-float output span (16B-aligned: (b*160+w0)*401*4 % 16 == 0), so zero
// and writeback are float4-vectorized. Depth loads grouped 4-consecutive
// per 4 lanes (16B segments) instead of 1 dword per 64B line.

#define BB 16
#define HH 120
#define WW 160
#define DD 401
#define WT 4                    // columns per block
#define NCOL (WT * DD)          // 1604 floats per block
#define NV4 (NCOL / 4)          // 401 float4s

#define DEPTH_MAX 8000.0f
#define INV_BIN 0.05f           // 1/20
#define SIG_EPS 0.50000001f     // sigma + 1e-8
#define ZERO_EPS 1e-6f

__global__ __launch_bounds__(256)
void dim_bev_kernel(const float* __restrict__ depth, float* __restrict__ out) {
    __shared__ __align__(16) float hist[NCOL];   // [wi][bin] flat
    const int bi = blockIdx.x;                   // b*40 + wtile
    const int b  = bi / 40;
    const int w0 = (bi - b * 40) * WT;
    const int tid = threadIdx.x;

    // zero LDS histogram, vectorized
    float4* h4 = (float4*)hist;
    for (int i = tid; i < NV4; i += 256)
        h4[i] = make_float4(0.f, 0.f, 0.f, 0.f);
    __syncthreads();

    // load 120 x 4 depth tile and scatter
    const float* dbase = depth + (size_t)b * HH * WW + w0;
    for (int idx = tid; idx < HH * WT; idx += 256) {
        const int h  = idx >> 2;
        const int wi = idx & 3;
        const float d = dbase[h * WW + wi];
        if (isfinite(d) && (d <= DEPTH_MAX) && (d > ZERO_EPS)) {
            int bin = __float2int_rn(d * INV_BIN);
            bin = bin < 0 ? 0 : (bin > DD - 1 ? DD - 1 : bin);
            const float x = (float)bin * 20.0f - d;
            const float z = x * (1.0f / SIG_EPS);
            const float norm = 1.0f / (SIG_EPS * 2.50662827463100050242f);
            const float g = __expf(-0.5f * z * z) * norm;
            if (g > 0.0f) atomicAdd(&hist[wi * DD + bin], g);
        }
    }
    __syncthreads();

    // vectorized contiguous writeback: hist flat == out[(b,w0..w0+3,:)] flat
    float4* o4 = (float4*)(out + ((size_t)b * WW + w0) * DD);
    for (int i = tid; i < NV4; i += 256)
        o4[i] = h4[i];
}

extern "C" void kernel_launch(void* const* d_in, const int* in_sizes, int n_in,
                              void* d_out, int out_size, void* d_ws, size_t ws_size,
                              hipStream_t stream) {
    const float* depth = (const float*)d_in[0];
    float* out = (float*)d_out;
    dim_bev_kernel<<<BB * (WW / WT), 256, 0, stream>>>(depth, out);
}